// Round 1
// baseline (532.718 us; speedup 1.0000x reference)
//
#include <hip/hip_runtime.h>
#include <stdint.h>
#include <math.h>

// ---------------- types ----------------
typedef __attribute__((ext_vector_type(4))) float f32x4;
typedef __attribute__((ext_vector_type(8))) short s16x8;   // 8 x bf16 (4 VGPRs)
typedef __attribute__((ext_vector_type(4))) unsigned short u16x4;

__device__ __forceinline__ unsigned short f2b(float x) {
    union { float f; uint32_t u; } v; v.f = x;
    uint32_t r = v.u + 0x7FFFu + ((v.u >> 16) & 1u);   // round-to-nearest-even
    return (unsigned short)(r >> 16);
}

__device__ __forceinline__ void gload16(const unsigned short* g, unsigned short* l) {
    __builtin_amdgcn_global_load_lds(
        (const __attribute__((address_space(1))) unsigned int*)(const void*)g,
        (__attribute__((address_space(3))) unsigned int*)(void*)l,
        16, 0, 0);
}

// ---------------- fp32 -> bf16 cast ----------------
__global__ __launch_bounds__(256) void cast_kernel(const float* __restrict__ in,
                                                   unsigned short* __restrict__ out,
                                                   int n4) {
    int i = blockIdx.x * 256 + threadIdx.x;
    if (i >= n4) return;
    f32x4 v = ((const f32x4*)in)[i];
    u16x4 o;
    #pragma unroll
    for (int j = 0; j < 4; ++j) o[j] = f2b(v[j]);
    ((u16x4*)out)[i] = o;
}

// ---------------- LayerNorm (C=1024), fp32 in -> bf16 out ----------------
__global__ __launch_bounds__(256) void ln_kernel(const float* __restrict__ x,
                                                 const float* __restrict__ w,
                                                 const float* __restrict__ b,
                                                 unsigned short* __restrict__ out) {
    const long row = blockIdx.x;
    const int tid = threadIdx.x;
    f32x4 v = *(const f32x4*)(x + row * 1024 + tid * 4);
    float s  = v[0] + v[1] + v[2] + v[3];
    float sq = v[0]*v[0] + v[1]*v[1] + v[2]*v[2] + v[3]*v[3];
    #pragma unroll
    for (int off = 32; off; off >>= 1) {
        s  += __shfl_xor(s, off);
        sq += __shfl_xor(sq, off);
    }
    __shared__ float red[8];
    if ((tid & 63) == 0) { red[tid >> 6] = s; red[4 + (tid >> 6)] = sq; }
    __syncthreads();
    s  = red[0] + red[1] + red[2] + red[3];
    sq = red[4] + red[5] + red[6] + red[7];
    float mu  = s * (1.0f / 1024.0f);
    float var = sq * (1.0f / 1024.0f) - mu * mu;
    float rs  = rsqrtf(var + 1e-5f);
    f32x4 wv = *(const f32x4*)(w + tid * 4);
    f32x4 bv = *(const f32x4*)(b + tid * 4);
    u16x4 o;
    #pragma unroll
    for (int j = 0; j < 4; ++j) o[j] = f2b((v[j] - mu) * rs * wv[j] + bv[j]);
    *(u16x4*)(out + row * 1024 + tid * 4) = o;
}

// ---------------- row softmax over 1024, fp32 in-place + bf16 copy ----------------
__global__ __launch_bounds__(256) void softmax_kernel(float* __restrict__ att,
                                                      unsigned short* __restrict__ attb) {
    const long row = blockIdx.x;
    const int tid = threadIdx.x;
    float* p = att + row * 1024;
    f32x4 v = *(const f32x4*)(p + tid * 4);
    float mx = fmaxf(fmaxf(v[0], v[1]), fmaxf(v[2], v[3]));
    #pragma unroll
    for (int off = 32; off; off >>= 1) mx = fmaxf(mx, __shfl_xor(mx, off));
    __shared__ float red[8];
    if ((tid & 63) == 0) red[tid >> 6] = mx;
    __syncthreads();
    mx = fmaxf(fmaxf(red[0], red[1]), fmaxf(red[2], red[3]));
    float s = 0.0f;
    #pragma unroll
    for (int j = 0; j < 4; ++j) { v[j] = __expf(v[j] - mx); s += v[j]; }
    #pragma unroll
    for (int off = 32; off; off >>= 1) s += __shfl_xor(s, off);
    if ((tid & 63) == 0) red[4 + (tid >> 6)] = s;
    __syncthreads();
    s = red[4] + red[5] + red[6] + red[7];
    float inv = 1.0f / s;
    u16x4 o;
    #pragma unroll
    for (int j = 0; j < 4; ++j) { v[j] *= inv; o[j] = f2b(v[j]); }
    *(f32x4*)(p + tid * 4) = v;
    *(u16x4*)(attb + row * 1024 + tid * 4) = o;
}

// ---------------- GEMM: C[n,m] = sum_k A[n,k] * B[m,k]  (both row-major over K) --------
// EPI: 0=QKV scatter, 1=scores(+mask)->f32, 2=PV scatter bf16, 3=bias+resid->f32,
//      4=bias+GELU->bf16, 5=bias+resid->f32 (final out)
template <int BM, int BN, int EPI>
__global__ __launch_bounds__(256)
void gemm_bt(const unsigned short* __restrict__ A,
             const unsigned short* __restrict__ Bm,
             int K, int lda, int ldb, int ldc,
             long sAz, long sBz,
             const float* __restrict__ bias,
             const float* __restrict__ resid,
             const float* __restrict__ mask,
             float* __restrict__ outF,
             unsigned short* __restrict__ outB) {
    constexpr int WM = BM / 2, WN = BN / 2;
    constexpr int FM = WM / 16, FN = WN / 16;
    __shared__ unsigned short ldsA[BM * 32];
    __shared__ unsigned short ldsB[BN * 32];

    const int tid  = threadIdx.x;
    const int lane = tid & 63;
    const int wid  = tid >> 6;
    const int wr   = wid >> 1, wc = wid & 1;
    const int bz   = blockIdx.z;
    const int row0 = blockIdx.x * BM;
    const int col0 = blockIdx.y * BN;

    const unsigned short* Ab = A + (long)bz * sAz + (long)row0 * lda;
    const unsigned short* Bb = Bm + (long)bz * sBz + (long)col0 * ldb;

    f32x4 acc[FM][FN] = {};
    const int fr = lane & 15;
    const int fk = (lane >> 4) * 8;

    for (int k0 = 0; k0 < K; k0 += 32) {
        #pragma unroll
        for (int i = 0; i < BM / 64; ++i) {
            int e = i * 2048 + wid * 512 + lane * 8;
            gload16(Ab + k0 + (long)(e >> 5) * lda + (e & 31),
                    &ldsA[i * 2048 + wid * 512]);
        }
        #pragma unroll
        for (int i = 0; i < BN / 64; ++i) {
            int e = i * 2048 + wid * 512 + lane * 8;
            gload16(Bb + k0 + (long)(e >> 5) * ldb + (e & 31),
                    &ldsB[i * 2048 + wid * 512]);
        }
        asm volatile("s_waitcnt vmcnt(0)" ::: "memory");
        __syncthreads();

        s16x8 af[FM], bfr[FN];
        #pragma unroll
        for (int m = 0; m < FM; ++m)
            af[m] = *(const s16x8*)&ldsA[(wr * WM + m * 16 + fr) * 32 + fk];
        #pragma unroll
        for (int n = 0; n < FN; ++n)
            bfr[n] = *(const s16x8*)&ldsB[(wc * WN + n * 16 + fr) * 32 + fk];
        #pragma unroll
        for (int m = 0; m < FM; ++m)
            #pragma unroll
            for (int n = 0; n < FN; ++n)
                acc[m][n] = __builtin_amdgcn_mfma_f32_16x16x32_bf16(af[m], bfr[n], acc[m][n], 0, 0, 0);
        __syncthreads();
    }

    // epilogue: D mapping col=lane&15, row=(lane>>4)*4+reg  [m89-verified]
    const int cj = lane & 15;
    const int r0 = (lane >> 4) * 4;
    #pragma unroll
    for (int m = 0; m < FM; ++m) {
        #pragma unroll
        for (int n = 0; n < FN; ++n) {
            #pragma unroll
            for (int r = 0; r < 4; ++r) {
                const int grow = row0 + wr * WM + m * 16 + r0 + r;
                const int gcol = col0 + wc * WN + n * 16 + cj;
                float v = acc[m][n][r];
                if constexpr (EPI == 0) {
                    // QKV scatter: q scaled 1/8 -> [BH,T,64]; k -> [BH,T,64]; v -> vT [BH,64,T]
                    v += bias[gcol];
                    const int bb = grow >> 10, t = grow & 1023;
                    const int seg = gcol >> 10, mm = gcol & 1023;
                    const int hh = mm >> 6, dd = mm & 63;
                    const long bh = bb * 16 + hh;
                    if (seg == 0)
                        outB[(bh << 16) + (t << 6) + dd] = f2b(v * 0.125f);
                    else if (seg == 1)
                        outB[4194304 + (bh << 16) + (t << 6) + dd] = f2b(v);
                    else
                        outB[8388608 + (bh << 16) + (dd << 10) + t] = f2b(v);
                } else if constexpr (EPI == 1) {
                    outF[((long)bz << 20) + ((long)grow << 10) + gcol] =
                        v + mask[((long)grow << 10) + gcol];
                } else if constexpr (EPI == 2) {
                    const int bb = bz >> 4, hh = bz & 15;
                    outB[((long)((bb << 10) | grow) << 10) + (hh << 6) + gcol] = f2b(v);
                } else if constexpr (EPI == 3 || EPI == 5) {
                    const long idx = ((long)grow << 10) + gcol;   // ldc = 1024
                    outF[idx] = v + bias[gcol] + resid[idx];
                } else if constexpr (EPI == 4) {
                    float u = v + bias[gcol];
                    float g = 0.5f * u * (1.0f + erff(u * 0.70710678118f));
                    outB[(long)grow * ldc + gcol] = f2b(g);
                }
            }
        }
    }
}

// ---------------- launch ----------------
extern "C" void kernel_launch(void* const* d_in, const int* in_sizes, int n_in,
                              void* d_out, int out_size, void* d_ws, size_t ws_size,
                              hipStream_t stream) {
    (void)in_sizes; (void)n_in; (void)out_size; (void)ws_size;
    const float* x     = (const float*)d_in[0];
    const float* mask  = (const float*)d_in[1];
    const float* ln1w  = (const float*)d_in[2];
    const float* ln1b  = (const float*)d_in[3];
    const float* wqkv  = (const float*)d_in[4];
    const float* bqkv  = (const float*)d_in[5];
    const float* wo    = (const float*)d_in[6];
    const float* bo    = (const float*)d_in[7];
    const float* ln2w  = (const float*)d_in[8];
    const float* ln2b  = (const float*)d_in[9];
    const float* wfc   = (const float*)d_in[10];
    const float* bfc   = (const float*)d_in[11];
    const float* wproj = (const float*)d_in[12];
    const float* bproj = (const float*)d_in[13];

    float* outx = (float*)d_out;                     // [4096,1024] fp32
    float* att  = (float*)d_out + 4194304;           // [64,1024,1024] fp32

    char* ws = (char*)d_ws;
    unsigned short* h_bf     = (unsigned short*)ws;  ws += (size_t)8  << 20;  // [4096,1024]
    unsigned short* wqkv_bf  = (unsigned short*)ws;  ws += (size_t)6  << 20;  // [3072,1024]
    unsigned short* wo_bf    = (unsigned short*)ws;  ws += (size_t)2  << 20;  // [1024,1024]
    unsigned short* wfc_bf   = (unsigned short*)ws;  ws += (size_t)8  << 20;  // [4096,1024]
    unsigned short* wproj_bf = (unsigned short*)ws;  ws += (size_t)8  << 20;  // [1024,4096]
    unsigned short* q_bf     = (unsigned short*)ws;  ws += (size_t)24 << 20;  // q,k,vT contiguous
    unsigned short* k_bf     = q_bf + 4194304;
    unsigned short* vT_bf    = q_bf + 8388608;
    unsigned short* att_bf   = (unsigned short*)ws;  ws += (size_t)128 << 20; // [64,1024,1024]
    unsigned short* y_bf     = (unsigned short*)ws;  ws += (size_t)8  << 20;  // [4096,1024]
    float*          x2       = (float*)ws;           ws += (size_t)16 << 20;  // [4096,1024] f32
    unsigned short* gelu_bf  = (unsigned short*)ws;  ws += (size_t)32 << 20;  // [4096,4096]

    // weights -> bf16
    cast_kernel<<<3072, 256, 0, stream>>>(wqkv,  wqkv_bf,  786432);
    cast_kernel<<<1024, 256, 0, stream>>>(wo,    wo_bf,    262144);
    cast_kernel<<<4096, 256, 0, stream>>>(wfc,   wfc_bf,   1048576);
    cast_kernel<<<4096, 256, 0, stream>>>(wproj, wproj_bf, 1048576);

    // LN1
    ln_kernel<<<4096, 256, 0, stream>>>(x, ln1w, ln1b, h_bf);

    // QKV: [4096,1024] x [3072,1024]^T
    gemm_bt<128, 128, 0><<<dim3(32, 24, 1), 256, 0, stream>>>(
        h_bf, wqkv_bf, 1024, 1024, 1024, 0, 0, 0,
        bqkv, nullptr, nullptr, nullptr, q_bf);

    // scores: per (b,h): [1024,64] x [1024,64]^T -> att (pre-softmax, +mask)
    gemm_bt<128, 128, 1><<<dim3(8, 8, 64), 256, 0, stream>>>(
        q_bf, k_bf, 64, 64, 64, 1024, 65536, 65536,
        nullptr, nullptr, mask, att, nullptr);

    // softmax rows (in-place fp32 + bf16 copy)
    softmax_kernel<<<65536, 256, 0, stream>>>(att, att_bf);

    // PV: per (b,h): [1024,1024] x [64,1024]^T -> y [B,T,C]
    gemm_bt<128, 64, 2><<<dim3(8, 1, 64), 256, 0, stream>>>(
        att_bf, vT_bf, 1024, 1024, 1024, 0, 1048576, 65536,
        nullptr, nullptr, nullptr, nullptr, y_bf);

    // W_o: [4096,1024] x [1024,1024]^T + b_o + x -> x2
    gemm_bt<128, 128, 3><<<dim3(32, 8, 1), 256, 0, stream>>>(
        y_bf, wo_bf, 1024, 1024, 1024, 1024, 0, 0,
        bo, x, nullptr, x2, nullptr);

    // LN2
    ln_kernel<<<4096, 256, 0, stream>>>(x2, ln2w, ln2b, h_bf);

    // FC + GELU: [4096,1024] x [4096,1024]^T -> gelu_bf [4096,4096]
    gemm_bt<128, 128, 4><<<dim3(32, 32, 1), 256, 0, stream>>>(
        h_bf, wfc_bf, 1024, 1024, 1024, 4096, 0, 0,
        bfc, nullptr, nullptr, nullptr, gelu_bf);

    // Proj: [4096,4096] x [1024,4096]^T + b_proj + x2 -> out
    gemm_bt<128, 128, 5><<<dim3(32, 8, 1), 256, 0, stream>>>(
        gelu_bf, wproj_bf, 4096, 4096, 4096, 1024, 0, 0,
        bproj, x2, nullptr, outx, nullptr);
}